// Round 10
// baseline (245.386 us; speedup 1.0000x reference)
//
#include <hip/hip_runtime.h>
#include <hip/hip_bf16.h>
#include <math.h>

typedef __hip_bfloat16 bf16;
typedef __attribute__((ext_vector_type(4))) float f32x4;
typedef __attribute__((ext_vector_type(8))) short bf16x8s;

#define T_SEQ 4096
#define MFMA16(a, b, c) __builtin_amdgcn_mfma_f32_16x16x32_bf16(a, b, c, 0, 0, 0)
#define AS1 __attribute__((address_space(1)))
#define AS3 __attribute__((address_space(3)))

static __device__ __forceinline__ float bf2f(short u) {
    return __uint_as_float(((unsigned int)(unsigned short)u) << 16);
}
static __device__ __forceinline__ short f2bf(float f) {
    bf16 h = __float2bfloat16(f);
    union { bf16 b; short s; } c; c.b = h; return c.s;
}
static __device__ __forceinline__ int swz_f(int r) { return (r & 7) ^ (r >> 3); }

// ---------------- f32 -> bf16 conversion (vectorized) ----------------
__global__ void cvt_f32_bf16(const float* __restrict__ src, bf16* __restrict__ dst, int n8) {
    int i = blockIdx.x * 256 + threadIdx.x;
    if (i >= n8) return;
    f32x4 a = ((const f32x4*)src)[(size_t)i * 2];
    f32x4 b = ((const f32x4*)src)[(size_t)i * 2 + 1];
    union { bf16 h[8]; uint4 u; } p;
    p.h[0] = __float2bfloat16(a.x); p.h[1] = __float2bfloat16(a.y);
    p.h[2] = __float2bfloat16(a.z); p.h[3] = __float2bfloat16(a.w);
    p.h[4] = __float2bfloat16(b.x); p.h[5] = __float2bfloat16(b.y);
    p.h[6] = __float2bfloat16(b.z); p.h[7] = __float2bfloat16(b.w);
    ((uint4*)dst)[i] = p.u;
}

// ============ 256x256 tile, BK=64, 8-wave deep-pipelined bf16 GEMM ============
// MODE 0 (N-grid 12): bx<4 -> Q block: softmax(row)*0.125 in f32, write Qb bf16.
//                     bx>=4 -> KV block j=bx-4; epilogue: per-(bucket,head) ksum
//                     (register-reduced) + ctx = K^T V via LDS restage + MFMA.
// MODE 1: plain f32 output.
// MFMA_BLOCK relies on compiler fine-grained lgkmcnt (C++ ds_reads); buffer
// reuse safe: reads consumed (=> complete) before closing barrier, overwriting
// GLL issued only after it; staged-data visibility gated by counted vmcnt(4).
template<int MODE>
__global__ __launch_bounds__(512, 2)
void gemm256(const bf16* __restrict__ A, const bf16* __restrict__ Bm,
             int K, int N,
             bf16* __restrict__ out0, bf16* __restrict__ ctxb, float* __restrict__ ksum,
             float* __restrict__ outf)
{
    __shared__ __align__(16) short SMEM[65536];   // A: (buf*2+kh)*8192 ; B: +32768
    const int tid  = threadIdx.x;
    const int l    = tid & 63;
    const int wid  = tid >> 6;
    const int wr   = wid >> 2;           // 0..1
    const int wc   = wid & 3;            // 0..3

    // XCD-chunked bijective swizzle (grid % 8 == 0)
    const int nwg  = gridDim.x * gridDim.y;
    const int flat = blockIdx.y * gridDim.x + blockIdx.x;
    const int swzb = (flat & 7) * (nwg >> 3) + (flat >> 3);
    const int bx   = swzb % gridDim.x;
    const int by   = swzb / gridDim.x;
    const int brow = by * 256;
    const int bcol = bx * 256;
    const int nkt  = K >> 6;             // must be even

    const bool isKV = (MODE == 0) && (bx >= 4);
    const int  jkv  = bx - 4;
    const int  b0row = isKV ? (1024 + jkv * 128) : bcol;
    const int  b1row = isKV ? (2048 + jkv * 128) : bcol + 128;

    const int chnk = (l >> 4) ^ (((l & 15) >> 1) & 3);
    const short* baseA = &SMEM[(wr * 128 + (l & 15)) * 32 + chnk * 8];
    const short* baseB = &SMEM[32768 + (wc * 64 + (l & 15)) * 32 + chnk * 8];
#define RDA(BUF, KH, M_) (*(const bf16x8s*)(baseA + (BUF) * 16384 + (KH) * 8192 + (M_) * 512))
#define RDB(BUF, KH, N_) (*(const bf16x8s*)(baseB + (BUF) * 16384 + (KH) * 8192 + (N_) * 512))

    const int srow = tid >> 2;
    const int scs  = (tid & 3) ^ ((srow >> 1) & 3);
    const bf16* gA0 = A  + (size_t)(brow + srow) * K + scs * 8;
    const bf16* gA1 = A  + (size_t)(brow + 128 + srow) * K + scs * 8;
    const bf16* gB0 = Bm + (size_t)(b0row + srow) * K + scs * 8;
    const bf16* gB1 = Bm + (size_t)(b1row + srow) * K + scs * 8;
#define GLL(PTR, KH, BUF, ISB, EXTRA)                                             \
    __builtin_amdgcn_global_load_lds((const AS1 void*)((PTR) + (KH) * 32),        \
        (AS3 void*)&SMEM[(ISB) * 32768 + ((BUF) * 2 + (KH)) * 8192 + (EXTRA) + tid * 8], 16, 0, 0)

    f32x4 acc[8][4];
#pragma unroll
    for (int m = 0; m < 8; ++m)
#pragma unroll
        for (int n = 0; n < 4; ++n) acc[m][n] = (f32x4){0.f, 0.f, 0.f, 0.f};

    GLL(gA0, 0, 0, 0, 0);    GLL(gA1, 0, 0, 0, 4096);
    GLL(gB0, 0, 0, 1, 0);    GLL(gB1, 0, 0, 1, 4096);
    GLL(gA0, 1, 0, 0, 0);    GLL(gA1, 1, 0, 0, 4096);
    GLL(gB0, 1, 0, 1, 0);    GLL(gB1, 1, 0, 1, 4096);
    asm volatile("s_waitcnt vmcnt(4)" ::: "memory");
    __builtin_amdgcn_s_barrier();

    const bf16 *pA0 = gA0 + 64, *pA1 = gA1 + 64, *pB0 = gB0 + 64, *pB1 = gB1 + 64;

#define MFMA_BLOCK(ACCOFF)                                                        \
    __builtin_amdgcn_s_barrier();                                                 \
    __builtin_amdgcn_s_setprio(1);                                                \
    _Pragma("unroll")                                                             \
    for (int m = 0; m < 4; ++m)                                                   \
        _Pragma("unroll")                                                         \
        for (int n = 0; n < 4; ++n)                                               \
            acc[m + (ACCOFF)][n] = MFMA16(afr[m], bfr[n], acc[m + (ACCOFF)][n]);  \
    __builtin_amdgcn_s_setprio(0);                                                \
    __builtin_amdgcn_s_barrier();

#define BODY(CUR, NXT, TT)                                                        \
    {                                                                             \
        const bool pf = ((TT) + 1 < nkt);                                         \
        bf16x8s afr[4], bfr[4];                                                   \
        _Pragma("unroll") for (int n = 0; n < 4; ++n) bfr[n] = RDB(CUR, 0, n);    \
        _Pragma("unroll") for (int m = 0; m < 4; ++m) afr[m] = RDA(CUR, 0, m);    \
        if (pf) { GLL(pA0, 0, NXT, 0, 0); GLL(pA1, 0, NXT, 0, 4096); }            \
        MFMA_BLOCK(0)                                                             \
        _Pragma("unroll") for (int m = 0; m < 4; ++m) afr[m] = RDA(CUR, 0, m + 4);\
        if (pf) { GLL(pB0, 0, NXT, 1, 0); GLL(pB1, 0, NXT, 1, 4096); }            \
        asm volatile("s_waitcnt vmcnt(4)" ::: "memory");                          \
        MFMA_BLOCK(4)                                                             \
        _Pragma("unroll") for (int n = 0; n < 4; ++n) bfr[n] = RDB(CUR, 1, n);    \
        _Pragma("unroll") for (int m = 0; m < 4; ++m) afr[m] = RDA(CUR, 1, m);    \
        if (pf) { GLL(pA0, 1, NXT, 0, 0); GLL(pA1, 1, NXT, 0, 4096); }            \
        MFMA_BLOCK(0)                                                             \
        _Pragma("unroll") for (int m = 0; m < 4; ++m) afr[m] = RDA(CUR, 1, m + 4);\
        if (pf) { GLL(pB0, 1, NXT, 1, 0); GLL(pB1, 1, NXT, 1, 4096); }            \
        asm volatile("s_waitcnt vmcnt(4)" ::: "memory");                          \
        MFMA_BLOCK(4)                                                             \
        pA0 += 64; pA1 += 64; pB0 += 64; pB1 += 64;                               \
    }

    for (int t = 0; t < nkt; t += 2) {
        BODY(0, 1, t)
        BODY(1, 0, t + 1)
    }

    if (MODE == 1) {
#pragma unroll
        for (int m = 0; m < 8; ++m) {
            int row = brow + wr * 128 + m * 16 + ((l >> 4) << 2);
#pragma unroll
            for (int n = 0; n < 4; ++n) {
                int col = bcol + wc * 64 + n * 16 + (l & 15);
#pragma unroll
                for (int r = 0; r < 4; ++r)
                    outf[(size_t)(row + r) * N + col] = acc[m][n][r];
            }
        }
    } else if (!isKV) {
        // ---- Q epilogue: f32 row-softmax over the 64-wide head (this wave's wc) ----
#pragma unroll
        for (int m = 0; m < 8; ++m) {
            int row = brow + wr * 128 + m * 16 + ((l >> 4) << 2);
#pragma unroll
            for (int r = 0; r < 4; ++r) {
                float v0 = acc[m][0][r], v1 = acc[m][1][r], v2 = acc[m][2][r], v3 = acc[m][3][r];
                float mx = fmaxf(fmaxf(v0, v1), fmaxf(v2, v3));
#pragma unroll
                for (int off = 8; off; off >>= 1) mx = fmaxf(mx, __shfl_xor(mx, off));
                float e0 = __expf(v0 - mx), e1 = __expf(v1 - mx);
                float e2 = __expf(v2 - mx), e3 = __expf(v3 - mx);
                float sm = e0 + e1 + e2 + e3;
#pragma unroll
                for (int off = 8; off; off >>= 1) sm += __shfl_xor(sm, off);
                float inv = 0.125f / sm;
                size_t rr = (size_t)(row + r);
                int cb = bcol + wc * 64 + (l & 15);
                out0[rr * 1024 + cb]      = __float2bfloat16(e0 * inv);
                out0[rr * 1024 + cb + 16] = __float2bfloat16(e1 * inv);
                out0[rr * 1024 + cb + 32] = __float2bfloat16(e2 * inv);
                out0[rr * 1024 + cb + 48] = __float2bfloat16(e3 * inv);
            }
        }
    } else {
        // ---- KV epilogue: packed b64 scatter + register ksum ----
        const int hl = wc & 1;                       // head_local (K: wc 0,1; V: wc 2,3)
        short* side = (short*)SMEM + ((wc >= 2) ? 32768 : 0);
        float ks[2][4];
#pragma unroll
        for (int u = 0; u < 2; ++u)
#pragma unroll
            for (int n = 0; n < 4; ++n) ks[u][n] = 0.f;
#pragma unroll
        for (int m = 0; m < 8; ++m) {
            const int ubase = wr * 16384 + (m >> 2) * 8192 + hl * 4096;  // unit*4096
            const int s0 = (m & 3) * 16 + ((l >> 4) << 2);
            const int sc = s0 >> 3, slo = s0 & 7;
#pragma unroll
            for (int n = 0; n < 4; ++n) {
                int d = n * 16 + (l & 15);
                union { short h4[4]; uint2 u2; } pk;
                if (wc < 2) {
                    float e0 = __expf(acc[m][n][0]), e1 = __expf(acc[m][n][1]);
                    float e2 = __expf(acc[m][n][2]), e3 = __expf(acc[m][n][3]);
                    ks[m >> 2][n] += (e0 + e1) + (e2 + e3);
                    pk.h4[0] = f2bf(e0); pk.h4[1] = f2bf(e1);
                    pk.h4[2] = f2bf(e2); pk.h4[3] = f2bf(e3);
                } else {
                    pk.h4[0] = f2bf(acc[m][n][0]); pk.h4[1] = f2bf(acc[m][n][1]);
                    pk.h4[2] = f2bf(acc[m][n][2]); pk.h4[3] = f2bf(acc[m][n][3]);
                }
                *(uint2*)&side[ubase + d * 64 + ((sc ^ swz_f(d)) << 3) + slo] = pk.u2;
            }
        }
        if (wc < 2) {   // finish ksum: lanes l, l^16, l^32 share d
#pragma unroll
            for (int u = 0; u < 2; ++u)
#pragma unroll
                for (int n = 0; n < 4; ++n) {
                    float s = ks[u][n];
                    s += __shfl_xor(s, 16);
                    s += __shfl_xor(s, 32);
                    if ((l >> 4) == 0) {
                        int unit = wr * 4 + u * 2 + hl;
                        int gr0 = brow + (unit >> 1) * 64;
                        size_t bidu = (size_t)(((gr0 >> 12) * 16) + jkv * 2 + (unit & 1)) * 64
                                      + ((gr0 & 4095) >> 6);
                        ksum[bidu * 64 + n * 16 + (l & 15)] = s;
                    }
                }
        }
        __syncthreads();

        // step 2: wave wid owns unit wid; ctx = K^T V (32 MFMA)
        const int gr0 = brow + (wid >> 1) * 64;
        const size_t bid = (size_t)(((gr0 >> 12) * 16) + jkv * 2 + (wid & 1)) * 64
                           + ((gr0 & 4095) >> 6);
        const short* k_u = (const short*)SMEM + wid * 4096;
        const short* v_u = (const short*)SMEM + 32768 + wid * 4096;

        f32x4 a16[4][4];
#pragma unroll
        for (int m = 0; m < 4; ++m)
#pragma unroll
            for (int n = 0; n < 4; ++n) a16[m][n] = (f32x4){0.f, 0.f, 0.f, 0.f};
#pragma unroll
        for (int kk = 0; kk < 2; ++kk) {
            const int cc = kk * 4 + (l >> 4);
            bf16x8s af[4], bf[4];
#pragma unroll
            for (int m = 0; m < 4; ++m) {
                int rA = m * 16 + (l & 15);
                af[m] = *(const bf16x8s*)&k_u[rA * 64 + ((cc ^ swz_f(rA)) << 3)];
                bf[m] = *(const bf16x8s*)&v_u[rA * 64 + ((cc ^ swz_f(rA)) << 3)];
            }
#pragma unroll
            for (int m = 0; m < 4; ++m)
#pragma unroll
                for (int n = 0; n < 4; ++n)
                    a16[m][n] = MFMA16(af[m], bf[n], a16[m][n]);
        }
        bf16* rec = ctxb + bid * 4096;
#pragma unroll
        for (int m = 0; m < 4; ++m) {
            int d0 = m * 16 + ((l >> 4) << 2);
#pragma unroll
            for (int n = 0; n < 4; ++n) {
                int e = n * 16 + (l & 15);
                ushort4 o;
                o.x = (ushort)f2bf(a16[m][n][0]); o.y = (ushort)f2bf(a16[m][n][1]);
                o.z = (ushort)f2bf(a16[m][n][2]); o.w = (ushort)f2bf(a16[m][n][3]);
                *(ushort4*)&rec[e * 64 + d0] = o;
            }
        }
    }
#undef RDA
#undef RDB
#undef GLL
#undef MFMA_BLOCK
#undef BODY
}

// ---------------- coarse scan: prefixes at 4-bucket granularity ----------------
// grid (5, 64): x<4 -> ctx quarters; x==4 -> ksum. C16/Ks16[bh][k], k=0..15 (k=0 zero).
__global__ void scan8(const bf16* __restrict__ ctxb, const float* __restrict__ ksum,
                      float* __restrict__ C16, float* __restrict__ Ks16)
{
    const int bh = blockIdx.y;
    if (blockIdx.x == 4) {
        int d = threadIdx.x;
        if (d >= 64) return;
        float run = 0.f;
        Ks16[(size_t)(bh * 16) * 64 + d] = 0.f;
        for (int j = 0; j < 60; ++j) {
            run += ksum[(size_t)(bh * 64 + j) * 64 + d];
            if ((j & 3) == 3) Ks16[(size_t)(bh * 16 + (j >> 2) + 1) * 64 + d] = run;
        }
        return;
    }
    int e0 = blockIdx.x * 1024 + threadIdx.x * 4;
    f32x4 run = {0.f, 0.f, 0.f, 0.f};
    *(f32x4*)&C16[(size_t)(bh * 16) * 4096 + e0] = run;
    for (int j = 0; j < 60; ++j) {
        ushort4 v = *(const ushort4*)&ctxb[(size_t)(bh * 64 + j) * 4096 + e0];
        run.x += bf2f((short)v.x); run.y += bf2f((short)v.y);
        run.z += bf2f((short)v.z); run.w += bf2f((short)v.w);
        if ((j & 3) == 3) *(f32x4*)&C16[(size_t)(bh * 16 + (j >> 2) + 1) * 4096 + e0] = run;
    }
}

// ---------------- fused scan + attn: running f32 prefix in LDS ----------------
// grid (16, 64) = (chunk ck, bh); 512 threads (8 waves); 4 buckets per block.
__global__ __launch_bounds__(512)
void attn_scan(const bf16* __restrict__ Qb, const bf16* __restrict__ ctxb,
               const float* __restrict__ ksum, const float* __restrict__ C16,
               const float* __restrict__ Ks16, bf16* __restrict__ attn)
{
    __shared__ __align__(16) float Pf[4096];     // [e*64+d] f32 running prefix
    __shared__ __align__(16) short ctb[4096];    // swizzled bf16 of Pf
    __shared__ __align__(16) short qb[4096];     // swizzled q
    __shared__ __align__(16) short at_s[64 * 72];
    __shared__ float kp[64];
    __shared__ float dinv[64];
    const int ck = blockIdx.x, bh = blockIdx.y;
    const int tid = threadIdx.x, l = tid & 63, w = tid >> 6;

    const size_t base16 = (size_t)(bh * 16 + ck) * 4096;
    *(f32x4*)&Pf[tid * 8]     = *(const f32x4*)&C16[base16 + tid * 8];
    *(f32x4*)&Pf[tid * 8 + 4] = *(const f32x4*)&C16[base16 + tid * 8 + 4];
    if (tid < 64) kp[tid] = Ks16[(size_t)(bh * 16 + ck) * 64 + tid];
    __syncthreads();

    const int b = bh >> 4, h = bh & 15;
    const int e_r = tid >> 3, dc_r = tid & 7;
    const int ctbaddr = e_r * 64 + ((dc_r ^ swz_f(e_r)) << 3);
    const int sg = w & 3, eh = w >> 2;

#pragma unroll 1
    for (int jj = 0; jj < 4; ++jj) {
        const int j = ck * 4 + jj;
        const size_t rowbase = ((size_t)(b * T_SEQ + j * 64)) * 1024 + h * 64;
        // (1) regen ctb from Pf (same-thread elems)
        {
            f32x4 lo = *(const f32x4*)&Pf[tid * 8];
            f32x4 hi = *(const f32x4*)&Pf[tid * 8 + 4];
            union { short h8[8]; uint4 u; } pk;
            pk.h8[0] = f2bf(lo.x); pk.h8[1] = f2bf(lo.y);
            pk.h8[2] = f2bf(lo.z); pk.h8[3] = f2bf(lo.w);
            pk.h8[4] = f2bf(hi.x); pk.h8[5] = f2bf(hi.y);
            pk.h8[6] = f2bf(hi.z); pk.h8[7] = f2bf(hi.w);
            *(uint4*)&ctb[ctbaddr] = pk.u;
        }
        // (2) q + den
#pragma unroll
        for (int i = 0; i < 8; ++i) {
            int s = w * 8 + i;
            float qv = bf2f(*(const short*)&Qb[rowbase + (size_t)s * 1024 + l]);
            float dp = qv * kp[l];
#pragma unroll
            for (int off = 32; off; off >>= 1) dp += __shfl_xor(dp, off);
            if (l == 0) dinv[s] = 1.f / fmaxf(dp, 1e-6f);
            qb[s * 64 + (((l >> 3) ^ swz_f(s)) << 3) + (l & 7)] = f2bf(qv);
        }
        __syncthreads();  // (3)
        // (4) MFMA: wave -> 16 s-rows (sg) x 32 e (eh)
        f32x4 acc2[2];
        acc2[0] = (f32x4){0.f, 0.f, 0.f, 0.f};
        acc2[1] = (f32x4){0.f, 0.f, 0.f, 0.f};
#pragma unroll
        for (int kk = 0; kk < 2; ++kk) {
            int cc = kk * 4 + (l >> 4);
            int sA = sg * 16 + (l & 15);
            bf16x8s af = *(const bf16x8s*)&qb[sA * 64 + ((cc ^ swz_f(sA)) << 3)];
#pragma unroll
            for (int n = 0; n < 2; ++n) {
                int e = eh * 32 + n * 16 + (l & 15);
                bf16x8s bf_ = *(const bf16x8s*)&ctb[e * 64 + ((cc ^ swz_f(e)) << 3)];
                acc2[n] = MFMA16(af, bf_, acc2[n]);
            }
        }
        // (4') exclusive-prefix update (after this bucket consumed it)
        {
            const size_t cb = (size_t)(bh * 64 + j) * 4096 + tid * 8;
            ushort4 v0 = *(const ushort4*)&ctxb[cb];
            ushort4 v1 = *(const ushort4*)&ctxb[cb + 4];
            f32x4 lo = *(const f32x4*)&Pf[tid * 8];
            f32x4 hi = *(const f32x4*)&Pf[tid * 8 + 4];
            lo.x += bf2f((short)v0.x); lo.y += bf2f((short)v0.y);
            lo.z += bf2f((short)v0.z); lo.w += bf2f((short)v0.w);
            hi.x += bf2f((short)v1.x); hi.y += bf2f((short)v1.y);
            hi.z += bf2f((short)v1.z); hi.w += bf2f((short)v1.w);
            *(f32x4*)&Pf[tid * 8]     = lo;
            *(f32x4*)&Pf[tid * 8 + 4] = hi;
        }
        if (tid < 64) kp[tid] += ksum[(size_t)(bh * 64 + j) * 64 + tid];
        // (5) scale + stage
#pragma unroll
        for (int n = 0; n < 2; ++n) {
            int e = eh * 32 + n * 16 + (l & 15);
#pragma unroll
            for (int r = 0; r < 4; ++r) {
                int s = sg * 16 + ((l >> 4) << 2) + r;
                at_s[s * 72 + e] = f2bf(acc2[n][r] * dinv[s]);
            }
        }
        __syncthreads();  // (6)
        // (7) coalesced store
        {
            int s = tid >> 3, c = tid & 7;
            bf16x8s vv = *(const bf16x8s*)&at_s[s * 72 + c * 8];
            *(bf16x8s*)&attn[rowbase + (size_t)s * 1024 + c * 8] = vv;
        }
    }
}

// ---------------- launch ----------------
extern "C" void kernel_launch(void* const* d_in, const int* in_sizes, int n_in,
                              void* d_out, int out_size, void* d_ws, size_t ws_size,
                              hipStream_t stream)
{
    const float* x    = (const float*)d_in[0];
    const float* Wqkv = (const float*)d_in[1];
    const float* Wout = (const float*)d_in[2];

    char* ws = (char*)d_ws;
    size_t off = 0;
    auto alloc = [&](size_t bytes) { void* p = ws + off; off += (bytes + 255) & ~(size_t)255; return p; };
    bf16*  xb    = (bf16*)alloc((size_t)16384 * 1024 * 2);
    bf16*  wqkvb = (bf16*)alloc((size_t)3072 * 1024 * 2);
    bf16*  woutb = (bf16*)alloc((size_t)1024 * 1024 * 2);
    bf16*  Qb    = (bf16*)alloc((size_t)16384 * 1024 * 2);
    bf16*  ctxb  = (bf16*)alloc((size_t)4096 * 4096 * 2);
    float* ksum  = (float*)alloc((size_t)4096 * 64 * 4);
    float* C16   = (float*)alloc((size_t)64 * 16 * 4096 * 4);
    float* Ks16  = (float*)alloc((size_t)64 * 16 * 64 * 4);
    bf16*  attnb = xb;                       // xb dead after GEMM1 -> reuse
    float* outf  = (float*)d_out;

    cvt_f32_bf16<<<dim3(16384 * 1024 / 8 / 256), 256, 0, stream>>>(x, xb, 16384 * 1024 / 8);
    cvt_f32_bf16<<<dim3(3072 * 1024 / 8 / 256), 256, 0, stream>>>(Wqkv, wqkvb, 3072 * 1024 / 8);
    cvt_f32_bf16<<<dim3(1024 * 1024 / 8 / 256), 256, 0, stream>>>(Wout, woutb, 1024 * 1024 / 8);

    gemm256<0><<<dim3(12, 64), 512, 0, stream>>>(xb, wqkvb, 1024, 3072, Qb, ctxb, ksum, nullptr);
    scan8<<<dim3(5, 64), 256, 0, stream>>>(ctxb, ksum, C16, Ks16);
    attn_scan<<<dim3(16, 64), 512, 0, stream>>>(Qb, ctxb, ksum, C16, Ks16, attnb);
    gemm256<1><<<dim3(4, 64), 512, 0, stream>>>(attnb, woutb, 1024, 1024, nullptr, nullptr, nullptr, outf);
}

// Round 12
// 239.640 us; speedup vs baseline: 1.0240x; 1.0240x over previous
//
#include <hip/hip_runtime.h>
#include <hip/hip_bf16.h>
#include <math.h>

typedef __hip_bfloat16 bf16;
typedef __attribute__((ext_vector_type(4))) float f32x4;
typedef __attribute__((ext_vector_type(8))) short bf16x8s;

#define T_SEQ 4096
#define MFMA16(a, b, c) __builtin_amdgcn_mfma_f32_16x16x32_bf16(a, b, c, 0, 0, 0)
#define AS1 __attribute__((address_space(1)))
#define AS3 __attribute__((address_space(3)))

static __device__ __forceinline__ float bf2f(short u) {
    return __uint_as_float(((unsigned int)(unsigned short)u) << 16);
}
static __device__ __forceinline__ short f2bf(float f) {
    bf16 h = __float2bfloat16(f);
    union { bf16 b; short s; } c; c.b = h; return c.s;
}
static __device__ __forceinline__ int swz_f(int r) { return (r & 7) ^ (r >> 3); }

// ---------------- f32 -> bf16 conversion (vectorized) ----------------
__global__ void cvt_f32_bf16(const float* __restrict__ src, bf16* __restrict__ dst, int n8) {
    int i = blockIdx.x * 256 + threadIdx.x;
    if (i >= n8) return;
    f32x4 a = ((const f32x4*)src)[(size_t)i * 2];
    f32x4 b = ((const f32x4*)src)[(size_t)i * 2 + 1];
    union { bf16 h[8]; uint4 u; } p;
    p.h[0] = __float2bfloat16(a.x); p.h[1] = __float2bfloat16(a.y);
    p.h[2] = __float2bfloat16(a.z); p.h[3] = __float2bfloat16(a.w);
    p.h[4] = __float2bfloat16(b.x); p.h[5] = __float2bfloat16(b.y);
    p.h[6] = __float2bfloat16(b.z); p.h[7] = __float2bfloat16(b.w);
    ((uint4*)dst)[i] = p.u;
}

// ============ 256x256 tile, BK=64, 8-wave pipelined bf16 GEMM ============
// 2 merged phases per K-tile (32 MFMA each): vmcnt(4) -> barrier -> sched_barrier(0)
// -> ds_read afr[8]/bfr[4] -> stage next tile's ksub (A+B, 4 GLL) -> 32 MFMA -> barrier.
// Ledger: prologue issues k0(0),k1(0) (8 loads). Phase (t,ks) opening vmcnt(4)
// completes k_ks(t) (the 4 oldest); issue k_ks(t+1) -> outstanding 4<->8, never 0.
// Tail (no prefetch): vmcnt(0).
// MODE 0 (N-grid 12): bx<4 Q block (f32 softmax epilogue); bx>=4 KV block (fused
// exp(K)/V -> ksum + ctx=K^T V, no K/V to HBM). MODE 1: plain f32 out.
template<int MODE>
__global__ __launch_bounds__(512, 2)
void gemm256(const bf16* __restrict__ A, const bf16* __restrict__ Bm,
             int K, int N,
             bf16* __restrict__ out0, bf16* __restrict__ ctxb, float* __restrict__ ksum,
             float* __restrict__ outf)
{
    __shared__ __align__(16) short SMEM[65536];   // A: (buf*2+kh)*8192 ; B: +32768
    const int tid  = threadIdx.x;
    const int l    = tid & 63;
    const int wid  = tid >> 6;
    const int wr   = wid >> 2;           // 0..1
    const int wc   = wid & 3;            // 0..3

    // XCD-chunked bijective swizzle (grid % 8 == 0)
    const int nwg  = gridDim.x * gridDim.y;
    const int flat = blockIdx.y * gridDim.x + blockIdx.x;
    const int swzb = (flat & 7) * (nwg >> 3) + (flat >> 3);
    const int bx   = swzb % gridDim.x;
    const int by   = swzb / gridDim.x;
    const int brow = by * 256;
    const int bcol = bx * 256;
    const int nkt  = K >> 6;             // must be even

    const bool isKV = (MODE == 0) && (bx >= 4);
    const int  jkv  = bx - 4;
    const int  b0row = isKV ? (1024 + jkv * 128) : bcol;
    const int  b1row = isKV ? (2048 + jkv * 128) : bcol + 128;

    const int chnk = (l >> 4) ^ (((l & 15) >> 1) & 3);
    const short* baseA = &SMEM[(wr * 128 + (l & 15)) * 32 + chnk * 8];
    const short* baseB = &SMEM[32768 + (wc * 64 + (l & 15)) * 32 + chnk * 8];
#define RDA(BUF, KH, M_) (*(const bf16x8s*)(baseA + (BUF) * 16384 + (KH) * 8192 + (M_) * 512))
#define RDB(BUF, KH, N_) (*(const bf16x8s*)(baseB + (BUF) * 16384 + (KH) * 8192 + (N_) * 512))

    const int srow = tid >> 2;
    const int scs  = (tid & 3) ^ ((srow >> 1) & 3);
    const bf16* gA0 = A  + (size_t)(brow + srow) * K + scs * 8;
    const bf16* gA1 = A  + (size_t)(brow + 128 + srow) * K + scs * 8;
    const bf16* gB0 = Bm + (size_t)(b0row + srow) * K + scs * 8;
    const bf16* gB1 = Bm + (size_t)(b1row + srow) * K + scs * 8;
#define GLL(PTR, KH, BUF, ISB, EXTRA)                                             \
    __builtin_amdgcn_global_load_lds((const AS1 void*)((PTR) + (KH) * 32),        \
        (AS3 void*)&SMEM[(ISB) * 32768 + ((BUF) * 2 + (KH)) * 8192 + (EXTRA) + tid * 8], 16, 0, 0)

    f32x4 acc[8][4];
#pragma unroll
    for (int m = 0; m < 8; ++m)
#pragma unroll
        for (int n = 0; n < 4; ++n) acc[m][n] = (f32x4){0.f, 0.f, 0.f, 0.f};

    // prologue: issue k0 (oldest 4) then k1 — no wait (phase 0 handles it)
    GLL(gA0, 0, 0, 0, 0);    GLL(gA1, 0, 0, 0, 4096);
    GLL(gB0, 0, 0, 1, 0);    GLL(gB1, 0, 0, 1, 4096);
    GLL(gA0, 1, 0, 0, 0);    GLL(gA1, 1, 0, 0, 4096);
    GLL(gB0, 1, 0, 1, 0);    GLL(gB1, 1, 0, 1, 4096);

    const bf16 *pA0 = gA0 + 64, *pA1 = gA1 + 64, *pB0 = gB0 + 64, *pB1 = gB1 + 64;

#define PHASE(CUR, NXT, KS, PF)                                                   \
    {                                                                             \
        bf16x8s afr[8], bfr[4];                                                   \
        if (PF) { asm volatile("s_waitcnt vmcnt(4)" ::: "memory"); }              \
        else    { asm volatile("s_waitcnt vmcnt(0)" ::: "memory"); }              \
        __builtin_amdgcn_s_barrier();                                             \
        __builtin_amdgcn_sched_barrier(0);                                        \
        _Pragma("unroll") for (int n = 0; n < 4; ++n) bfr[n] = RDB(CUR, KS, n);   \
        _Pragma("unroll") for (int m = 0; m < 8; ++m) afr[m] = RDA(CUR, KS, m);   \
        if (PF) { GLL(pA0, KS, NXT, 0, 0); GLL(pA1, KS, NXT, 0, 4096);            \
                  GLL(pB0, KS, NXT, 1, 0); GLL(pB1, KS, NXT, 1, 4096); }          \
        __builtin_amdgcn_s_setprio(1);                                            \
        _Pragma("unroll")                                                         \
        for (int m = 0; m < 8; ++m)                                               \
            _Pragma("unroll")                                                     \
            for (int n = 0; n < 4; ++n)                                           \
                acc[m][n] = MFMA16(afr[m], bfr[n], acc[m][n]);                    \
        __builtin_amdgcn_s_setprio(0);                                            \
        __builtin_amdgcn_s_barrier();                                             \
    }

#define BODY(CUR, NXT, TT)                                                        \
    {                                                                             \
        const bool pf = ((TT) + 1 < nkt);                                         \
        PHASE(CUR, NXT, 0, pf)                                                    \
        PHASE(CUR, NXT, 1, pf)                                                    \
        pA0 += 64; pA1 += 64; pB0 += 64; pB1 += 64;                               \
    }

    for (int t = 0; t < nkt; t += 2) {
        BODY(0, 1, t)
        BODY(1, 0, t + 1)
    }

    if (MODE == 1) {
#pragma unroll
        for (int m = 0; m < 8; ++m) {
            int row = brow + wr * 128 + m * 16 + ((l >> 4) << 2);
#pragma unroll
            for (int n = 0; n < 4; ++n) {
                int col = bcol + wc * 64 + n * 16 + (l & 15);
#pragma unroll
                for (int r = 0; r < 4; ++r)
                    outf[(size_t)(row + r) * N + col] = acc[m][n][r];
            }
        }
    } else if (!isKV) {
        // ---- Q epilogue: f32 row-softmax over the 64-wide head (this wave's wc) ----
#pragma unroll
        for (int m = 0; m < 8; ++m) {
            int row = brow + wr * 128 + m * 16 + ((l >> 4) << 2);
#pragma unroll
            for (int r = 0; r < 4; ++r) {
                float v0 = acc[m][0][r], v1 = acc[m][1][r], v2 = acc[m][2][r], v3 = acc[m][3][r];
                float mx = fmaxf(fmaxf(v0, v1), fmaxf(v2, v3));
#pragma unroll
                for (int off = 8; off; off >>= 1) mx = fmaxf(mx, __shfl_xor(mx, off));
                float e0 = __expf(v0 - mx), e1 = __expf(v1 - mx);
                float e2 = __expf(v2 - mx), e3 = __expf(v3 - mx);
                float sm = e0 + e1 + e2 + e3;
#pragma unroll
                for (int off = 8; off; off >>= 1) sm += __shfl_xor(sm, off);
                float inv = 0.125f / sm;
                size_t rr = (size_t)(row + r);
                int cb = bcol + wc * 64 + (l & 15);
                out0[rr * 1024 + cb]      = __float2bfloat16(e0 * inv);
                out0[rr * 1024 + cb + 16] = __float2bfloat16(e1 * inv);
                out0[rr * 1024 + cb + 32] = __float2bfloat16(e2 * inv);
                out0[rr * 1024 + cb + 48] = __float2bfloat16(e3 * inv);
            }
        }
    } else {
        // ---- KV epilogue: packed b64 scatter + register ksum ----
        const int hl = wc & 1;                       // head_local (K: wc 0,1; V: wc 2,3)
        short* side = (short*)SMEM + ((wc >= 2) ? 32768 : 0);
        float ks[2][4];
#pragma unroll
        for (int u = 0; u < 2; ++u)
#pragma unroll
            for (int n = 0; n < 4; ++n) ks[u][n] = 0.f;
#pragma unroll
        for (int m = 0; m < 8; ++m) {
            const int ubase = wr * 16384 + (m >> 2) * 8192 + hl * 4096;  // unit*4096
            const int s0 = (m & 3) * 16 + ((l >> 4) << 2);
            const int sc = s0 >> 3, slo = s0 & 7;
#pragma unroll
            for (int n = 0; n < 4; ++n) {
                int d = n * 16 + (l & 15);
                union { short h4[4]; uint2 u2; } pk;
                if (wc < 2) {
                    float e0 = __expf(acc[m][n][0]), e1 = __expf(acc[m][n][1]);
                    float e2 = __expf(acc[m][n][2]), e3 = __expf(acc[m][n][3]);
                    ks[m >> 2][n] += (e0 + e1) + (e2 + e3);
                    pk.h4[0] = f2bf(e0); pk.h4[1] = f2bf(e1);
                    pk.h4[2] = f2bf(e2); pk.h4[3] = f2bf(e3);
                } else {
                    pk.h4[0] = f2bf(acc[m][n][0]); pk.h4[1] = f2bf(acc[m][n][1]);
                    pk.h4[2] = f2bf(acc[m][n][2]); pk.h4[3] = f2bf(acc[m][n][3]);
                }
                *(uint2*)&side[ubase + d * 64 + ((sc ^ swz_f(d)) << 3) + slo] = pk.u2;
            }
        }
        if (wc < 2) {   // finish ksum: lanes l, l^16, l^32 share d
#pragma unroll
            for (int u = 0; u < 2; ++u)
#pragma unroll
                for (int n = 0; n < 4; ++n) {
                    float s = ks[u][n];
                    s += __shfl_xor(s, 16);
                    s += __shfl_xor(s, 32);
                    if ((l >> 4) == 0) {
                        int unit = wr * 4 + u * 2 + hl;
                        int gr0 = brow + (unit >> 1) * 64;
                        size_t bidu = (size_t)(((gr0 >> 12) * 16) + jkv * 2 + (unit & 1)) * 64
                                      + ((gr0 & 4095) >> 6);
                        ksum[bidu * 64 + n * 16 + (l & 15)] = s;
                    }
                }
        }
        __syncthreads();

        // step 2: wave wid owns unit wid; ctx = K^T V (32 MFMA)
        const int gr0 = brow + (wid >> 1) * 64;
        const size_t bid = (size_t)(((gr0 >> 12) * 16) + jkv * 2 + (wid & 1)) * 64
                           + ((gr0 & 4095) >> 6);
        const short* k_u = (const short*)SMEM + wid * 4096;
        const short* v_u = (const short*)SMEM + 32768 + wid * 4096;

        f32x4 a16[4][4];
#pragma unroll
        for (int m = 0; m < 4; ++m)
#pragma unroll
            for (int n = 0; n < 4; ++n) a16[m][n] = (f32x4){0.f, 0.f, 0.f, 0.f};
#pragma unroll
        for (int kk = 0; kk < 2; ++kk) {
            const int cc = kk * 4 + (l >> 4);
            bf16x8s af[4], bf[4];
#pragma unroll
            for (int m = 0; m < 4; ++m) {
                int rA = m * 16 + (l & 15);
                af[m] = *(const bf16x8s*)&k_u[rA * 64 + ((cc ^ swz_f(rA)) << 3)];
                bf[m] = *(const bf16x8s*)&v_u[rA * 64 + ((cc ^ swz_f(rA)) << 3)];
            }
#pragma unroll
            for (int m = 0; m < 4; ++m)
#pragma unroll
                for (int n = 0; n < 4; ++n)
                    a16[m][n] = MFMA16(af[m], bf[n], a16[m][n]);
        }
        bf16* rec = ctxb + bid * 4096;
#pragma unroll
        for (int m = 0; m < 4; ++m) {
            int d0 = m * 16 + ((l >> 4) << 2);
#pragma unroll
            for (int n = 0; n < 4; ++n) {
                int e = n * 16 + (l & 15);
                ushort4 o;
                o.x = (ushort)f2bf(a16[m][n][0]); o.y = (ushort)f2bf(a16[m][n][1]);
                o.z = (ushort)f2bf(a16[m][n][2]); o.w = (ushort)f2bf(a16[m][n][3]);
                *(ushort4*)&rec[e * 64 + d0] = o;
            }
        }
    }
#undef RDA
#undef RDB
#undef GLL
#undef PHASE
#undef BODY
}

// ---------------- exclusive cumsum over buckets ----------------
// grid (5, 64): x<4 -> ctx chains (bf16 in, f32 accum, bf16 out); x==4 -> ksum (f32)
__global__ void cumsum_excl(const bf16* __restrict__ ctxb, const float* __restrict__ ksum,
                            bf16* __restrict__ ctp, float* __restrict__ ksump)
{
    const int bh = blockIdx.y;
    if (blockIdx.x == 4) {
        int d = threadIdx.x;
        if (d >= 64) return;
        float run = 0.f;
        for (int j = 0; j < 64; ++j) {
            size_t idx = (size_t)(bh * 64 + j) * 64 + d;
            float v = ksum[idx];
            ksump[idx] = run;
            run += v;
        }
        return;
    }
    int e0 = (blockIdx.x * 256 + threadIdx.x) * 4;
    float r0 = 0.f, r1 = 0.f, r2 = 0.f, r3 = 0.f;
    for (int j = 0; j < 64; ++j) {
        size_t idx = (size_t)(bh * 64 + j) * 4096 + e0;
        ushort4 v = *(const ushort4*)&ctxb[idx];
        ushort4 o;
        o.x = (ushort)f2bf(r0); o.y = (ushort)f2bf(r1);
        o.z = (ushort)f2bf(r2); o.w = (ushort)f2bf(r3);
        *(ushort4*)&ctp[idx] = o;
        r0 += bf2f((short)v.x); r1 += bf2f((short)v.y);
        r2 += bf2f((short)v.z); r3 += bf2f((short)v.w);
    }
}

// ---------------- den + attn = q @ ctx * Dinv (q pre-softmaxed in GEMM1) ----------------
__global__ __launch_bounds__(256)
void bucket_attn(const bf16* __restrict__ Qb, const bf16* __restrict__ ctp,
                 const float* __restrict__ ksump, bf16* __restrict__ attn)
{
    __shared__ __align__(16) short q_bf[64 * 64];
    __shared__ __align__(16) short ct_bf[64 * 64];
    __shared__ __align__(16) short at_s[64 * 72];
    __shared__ float dinv_s[64];
    __shared__ float ksum_s[64];
    const int bid = blockIdx.x;
    const int bh = bid >> 6, n = bid & 63;
    const int b = bh >> 4, h = bh & 15;
    const size_t rowbase = (size_t)(b * T_SEQ + n * 64) * 1024 + h * 64;
    const int tid = threadIdx.x;
    const int l = tid & 63, w = tid >> 6;

#pragma unroll
    for (int j = 0; j < 2; ++j) {
        int i = tid + 256 * j;
        int e = i >> 3, dc = i & 7;
        bf16x8s cv = *(const bf16x8s*)&ctp[(size_t)bid * 4096 + e * 64 + dc * 8];
        *(bf16x8s*)&ct_bf[e * 64 + ((dc ^ swz_f(e)) << 3)] = cv;
    }
    if (tid < 64) ksum_s[tid] = ksump[(size_t)bid * 64 + tid];
    __syncthreads();

    // den reduce only (softmax already applied in GEMM1)
#pragma unroll
    for (int i = 0; i < 16; ++i) {
        int s = w * 16 + i;
        float qv = bf2f(*(const short*)&Qb[rowbase + (size_t)s * 1024 + l]);
        float dp = qv * ksum_s[l];
#pragma unroll
        for (int off = 32; off; off >>= 1) dp += __shfl_xor(dp, off);
        if (l == 0) dinv_s[s] = 1.f / fmaxf(dp, 1e-6f);
        q_bf[s * 64 + ((((l >> 3)) ^ swz_f(s)) << 3) + (l & 7)] = f2bf(qv);
    }
    __syncthreads();

    f32x4 acc[4];
#pragma unroll
    for (int i = 0; i < 4; ++i) acc[i] = (f32x4){0.f, 0.f, 0.f, 0.f};
    bf16x8s afr[2], bfr[2][4];
#pragma unroll
    for (int kk = 0; kk < 2; ++kk) {
        int cc = kk * 4 + (l >> 4);
        int r = w * 16 + (l & 15);
        afr[kk] = *(const bf16x8s*)&q_bf[r * 64 + ((cc ^ swz_f(r)) << 3)];
#pragma unroll
        for (int n4 = 0; n4 < 4; ++n4) {
            int e = n4 * 16 + (l & 15);
            bfr[kk][n4] = *(const bf16x8s*)&ct_bf[e * 64 + ((cc ^ swz_f(e)) << 3)];
        }
    }
#pragma unroll
    for (int kk = 0; kk < 2; ++kk)
#pragma unroll
        for (int n4 = 0; n4 < 4; ++n4)
            acc[n4] = MFMA16(afr[kk], bfr[kk][n4], acc[n4]);

#pragma unroll
    for (int n4 = 0; n4 < 4; ++n4) {
        int e = n4 * 16 + (l & 15);
#pragma unroll
        for (int r = 0; r < 4; ++r) {
            int s = w * 16 + ((l >> 4) << 2) + r;
            at_s[s * 72 + e] = f2bf(acc[n4][r] * dinv_s[s]);
        }
    }
    __syncthreads();

#pragma unroll
    for (int j = 0; j < 2; ++j) {
        int i = tid + 256 * j;
        int s = i >> 3, c = i & 7;
        bf16x8s v = *(const bf16x8s*)&at_s[s * 72 + c * 8];
        *(bf16x8s*)&attn[rowbase + (size_t)s * 1024 + c * 8] = v;
    }
}

// ---------------- launch ----------------
extern "C" void kernel_launch(void* const* d_in, const int* in_sizes, int n_in,
                              void* d_out, int out_size, void* d_ws, size_t ws_size,
                              hipStream_t stream)
{
    const float* x    = (const float*)d_in[0];
    const float* Wqkv = (const float*)d_in[1];
    const float* Wout = (const float*)d_in[2];

    char* ws = (char*)d_ws;
    size_t off = 0;
    auto alloc = [&](size_t bytes) { void* p = ws + off; off += (bytes + 255) & ~(size_t)255; return p; };
    bf16*  xb    = (bf16*)alloc((size_t)16384 * 1024 * 2);
    bf16*  wqkvb = (bf16*)alloc((size_t)3072 * 1024 * 2);
    bf16*  woutb = (bf16*)alloc((size_t)1024 * 1024 * 2);
    bf16*  Qb    = (bf16*)alloc((size_t)16384 * 1024 * 2);
    bf16*  ctxb  = (bf16*)alloc((size_t)4096 * 4096 * 2);
    float* ksum  = (float*)alloc((size_t)4096 * 64 * 4);
    bf16*  ctp   = (bf16*)alloc((size_t)4096 * 4096 * 2);
    float* ksump = (float*)alloc((size_t)4096 * 64 * 4);
    bf16*  attnb = xb;                       // xb dead after GEMM1 -> reuse
    float* outf  = (float*)d_out;

    cvt_f32_bf16<<<dim3(16384 * 1024 / 8 / 256), 256, 0, stream>>>(x, xb, 16384 * 1024 / 8);
    cvt_f32_bf16<<<dim3(3072 * 1024 / 8 / 256), 256, 0, stream>>>(Wqkv, wqkvb, 3072 * 1024 / 8);
    cvt_f32_bf16<<<dim3(1024 * 1024 / 8 / 256), 256, 0, stream>>>(Wout, woutb, 1024 * 1024 / 8);

    gemm256<0><<<dim3(12, 64), 512, 0, stream>>>(xb, wqkvb, 1024, 3072, Qb, ctxb, ksum, nullptr);
    cumsum_excl<<<dim3(5, 64), 256, 0, stream>>>(ctxb, ksum, ctp, ksump);
    bucket_attn<<<dim3(4096), 256, 0, stream>>>(Qb, ctp, ksump, attnb);
    gemm256<1><<<dim3(4, 64), 512, 0, stream>>>(attnb, woutb, 1024, 1024, nullptr, nullptr, nullptr, outf);
}

// Round 15
// 232.447 us; speedup vs baseline: 1.0557x; 1.0309x over previous
//
#include <hip/hip_runtime.h>
#include <hip/hip_bf16.h>
#include <math.h>

typedef __hip_bfloat16 bf16;
typedef __attribute__((ext_vector_type(4))) float f32x4;
typedef __attribute__((ext_vector_type(8))) short bf16x8s;

#define T_SEQ 4096
#define MFMA16(a, b, c) __builtin_amdgcn_mfma_f32_16x16x32_bf16(a, b, c, 0, 0, 0)
#define AS1 __attribute__((address_space(1)))
#define AS3 __attribute__((address_space(3)))

static __device__ __forceinline__ float bf2f(short u) {
    return __uint_as_float(((unsigned int)(unsigned short)u) << 16);
}
static __device__ __forceinline__ short f2bf(float f) {
    bf16 h = __float2bfloat16(f);
    union { bf16 b; short s; } c; c.b = h; return c.s;
}
static __device__ __forceinline__ int swz_f(int r) { return (r & 7) ^ (r >> 3); }

// ---------------- f32 -> bf16 conversion (vectorized) ----------------
__global__ void cvt_f32_bf16(const float* __restrict__ src, bf16* __restrict__ dst, int n8) {
    int i = blockIdx.x * 256 + threadIdx.x;
    if (i >= n8) return;
    f32x4 a = ((const f32x4*)src)[(size_t)i * 2];
    f32x4 b = ((const f32x4*)src)[(size_t)i * 2 + 1];
    union { bf16 h[8]; uint4 u; } p;
    p.h[0] = __float2bfloat16(a.x); p.h[1] = __float2bfloat16(a.y);
    p.h[2] = __float2bfloat16(a.z); p.h[3] = __float2bfloat16(a.w);
    p.h[4] = __float2bfloat16(b.x); p.h[5] = __float2bfloat16(b.y);
    p.h[6] = __float2bfloat16(b.z); p.h[7] = __float2bfloat16(b.w);
    ((uint4*)dst)[i] = p.u;
}

// ============ 256x256 tile, BK=64, 8-wave pipelined bf16 GEMM ============
// 4 phases per K-tile (r10-measured best: gemm<0> = 123.0 us). MFMA_BLOCK relies
// on compiler fine-grained lgkmcnt (C++ ds_reads); buffer reuse safe: reads
// consumed (=> complete) before closing barrier, overwriting GLL issued only
// after it; staged-data visibility gated by counted vmcnt(4).
// MODE 0 (N-grid 12): bx<4 Q block (f32 softmax epilogue); bx>=4 KV block (fused
// exp(K)/V -> ksum + ctx=K^T V, no K/V to HBM). MODE 1: plain f32 out.
template<int MODE>
__global__ __launch_bounds__(512, 2)
void gemm256(const bf16* __restrict__ A, const bf16* __restrict__ Bm,
             int K, int N,
             bf16* __restrict__ out0, bf16* __restrict__ ctxb, float* __restrict__ ksum,
             float* __restrict__ outf)
{
    __shared__ __align__(16) short SMEM[65536];   // A: (buf*2+kh)*8192 ; B: +32768
    const int tid  = threadIdx.x;
    const int l    = tid & 63;
    const int wid  = tid >> 6;
    const int wr   = wid >> 2;           // 0..1
    const int wc   = wid & 3;            // 0..3

    // XCD-chunked bijective swizzle (grid % 8 == 0)
    const int nwg  = gridDim.x * gridDim.y;
    const int flat = blockIdx.y * gridDim.x + blockIdx.x;
    const int swzb = (flat & 7) * (nwg >> 3) + (flat >> 3);
    const int bx   = swzb % gridDim.x;
    const int by   = swzb / gridDim.x;
    const int brow = by * 256;
    const int bcol = bx * 256;
    const int nkt  = K >> 6;             // must be even

    const bool isKV = (MODE == 0) && (bx >= 4);
    const int  jkv  = bx - 4;
    const int  b0row = isKV ? (1024 + jkv * 128) : bcol;
    const int  b1row = isKV ? (2048 + jkv * 128) : bcol + 128;

    const int chnk = (l >> 4) ^ (((l & 15) >> 1) & 3);
    const short* baseA = &SMEM[(wr * 128 + (l & 15)) * 32 + chnk * 8];
    const short* baseB = &SMEM[32768 + (wc * 64 + (l & 15)) * 32 + chnk * 8];
#define RDA(BUF, KH, M_) (*(const bf16x8s*)(baseA + (BUF) * 16384 + (KH) * 8192 + (M_) * 512))
#define RDB(BUF, KH, N_) (*(const bf16x8s*)(baseB + (BUF) * 16384 + (KH) * 8192 + (N_) * 512))

    const int srow = tid >> 2;
    const int scs  = (tid & 3) ^ ((srow >> 1) & 3);
    const bf16* gA0 = A  + (size_t)(brow + srow) * K + scs * 8;
    const bf16* gA1 = A  + (size_t)(brow + 128 + srow) * K + scs * 8;
    const bf16* gB0 = Bm + (size_t)(b0row + srow) * K + scs * 8;
    const bf16* gB1 = Bm + (size_t)(b1row + srow) * K + scs * 8;
#define GLL(PTR, KH, BUF, ISB, EXTRA)                                             \
    __builtin_amdgcn_global_load_lds((const AS1 void*)((PTR) + (KH) * 32),        \
        (AS3 void*)&SMEM[(ISB) * 32768 + ((BUF) * 2 + (KH)) * 8192 + (EXTRA) + tid * 8], 16, 0, 0)

    f32x4 acc[8][4];
#pragma unroll
    for (int m = 0; m < 8; ++m)
#pragma unroll
        for (int n = 0; n < 4; ++n) acc[m][n] = (f32x4){0.f, 0.f, 0.f, 0.f};

    GLL(gA0, 0, 0, 0, 0);    GLL(gA1, 0, 0, 0, 4096);
    GLL(gB0, 0, 0, 1, 0);    GLL(gB1, 0, 0, 1, 4096);
    GLL(gA0, 1, 0, 0, 0);    GLL(gA1, 1, 0, 0, 4096);
    GLL(gB0, 1, 0, 1, 0);    GLL(gB1, 1, 0, 1, 4096);
    asm volatile("s_waitcnt vmcnt(4)" ::: "memory");
    __builtin_amdgcn_s_barrier();

    const bf16 *pA0 = gA0 + 64, *pA1 = gA1 + 64, *pB0 = gB0 + 64, *pB1 = gB1 + 64;

#define MFMA_BLOCK(ACCOFF)                                                        \
    __builtin_amdgcn_s_barrier();                                                 \
    __builtin_amdgcn_s_setprio(1);                                                \
    _Pragma("unroll")                                                             \
    for (int m = 0; m < 4; ++m)                                                   \
        _Pragma("unroll")                                                         \
        for (int n = 0; n < 4; ++n)                                               \
            acc[m + (ACCOFF)][n] = MFMA16(afr[m], bfr[n], acc[m + (ACCOFF)][n]);  \
    __builtin_amdgcn_s_setprio(0);                                                \
    __builtin_amdgcn_s_barrier();

#define BODY(CUR, NXT, TT)                                                        \
    {                                                                             \
        const bool pf = ((TT) + 1 < nkt);                                         \
        bf16x8s afr[4], bfr[4];                                                   \
        _Pragma("unroll") for (int n = 0; n < 4; ++n) bfr[n] = RDB(CUR, 0, n);    \
        _Pragma("unroll") for (int m = 0; m < 4; ++m) afr[m] = RDA(CUR, 0, m);    \
        if (pf) { GLL(pA0, 0, NXT, 0, 0); GLL(pA1, 0, NXT, 0, 4096); }            \
        MFMA_BLOCK(0)                                                             \
        _Pragma("unroll") for (int m = 0; m < 4; ++m) afr[m] = RDA(CUR, 0, m + 4);\
        if (pf) { GLL(pB0, 0, NXT, 1, 0); GLL(pB1, 0, NXT, 1, 4096); }            \
        asm volatile("s_waitcnt vmcnt(4)" ::: "memory");                          \
        MFMA_BLOCK(4)                                                             \
        _Pragma("unroll") for (int n = 0; n < 4; ++n) bfr[n] = RDB(CUR, 1, n);    \
        _Pragma("unroll") for (int m = 0; m < 4; ++m) afr[m] = RDA(CUR, 1, m);    \
        if (pf) { GLL(pA0, 1, NXT, 0, 0); GLL(pA1, 1, NXT, 0, 4096); }            \
        MFMA_BLOCK(0)                                                             \
        _Pragma("unroll") for (int m = 0; m < 4; ++m) afr[m] = RDA(CUR, 1, m + 4);\
        if (pf) { GLL(pB0, 1, NXT, 1, 0); GLL(pB1, 1, NXT, 1, 4096); }            \
        asm volatile("s_waitcnt vmcnt(4)" ::: "memory");                          \
        MFMA_BLOCK(4)                                                             \
        pA0 += 64; pA1 += 64; pB0 += 64; pB1 += 64;                               \
    }

    for (int t = 0; t < nkt; t += 2) {
        BODY(0, 1, t)
        BODY(1, 0, t + 1)
    }

    if (MODE == 1) {
#pragma unroll
        for (int m = 0; m < 8; ++m) {
            int row = brow + wr * 128 + m * 16 + ((l >> 4) << 2);
#pragma unroll
            for (int n = 0; n < 4; ++n) {
                int col = bcol + wc * 64 + n * 16 + (l & 15);
#pragma unroll
                for (int r = 0; r < 4; ++r)
                    outf[(size_t)(row + r) * N + col] = acc[m][n][r];
            }
        }
    } else if (!isKV) {
        // ---- Q epilogue: f32 row-softmax over the 64-wide head (this wave's wc) ----
#pragma unroll
        for (int m = 0; m < 8; ++m) {
            int row = brow + wr * 128 + m * 16 + ((l >> 4) << 2);
#pragma unroll
            for (int r = 0; r < 4; ++r) {
                float v0 = acc[m][0][r], v1 = acc[m][1][r], v2 = acc[m][2][r], v3 = acc[m][3][r];
                float mx = fmaxf(fmaxf(v0, v1), fmaxf(v2, v3));
#pragma unroll
                for (int off = 8; off; off >>= 1) mx = fmaxf(mx, __shfl_xor(mx, off));
                float e0 = __expf(v0 - mx), e1 = __expf(v1 - mx);
                float e2 = __expf(v2 - mx), e3 = __expf(v3 - mx);
                float sm = e0 + e1 + e2 + e3;
#pragma unroll
                for (int off = 8; off; off >>= 1) sm += __shfl_xor(sm, off);
                float inv = 0.125f / sm;
                size_t rr = (size_t)(row + r);
                int cb = bcol + wc * 64 + (l & 15);
                out0[rr * 1024 + cb]      = __float2bfloat16(e0 * inv);
                out0[rr * 1024 + cb + 16] = __float2bfloat16(e1 * inv);
                out0[rr * 1024 + cb + 32] = __float2bfloat16(e2 * inv);
                out0[rr * 1024 + cb + 48] = __float2bfloat16(e3 * inv);
            }
        }
    } else {
        // ---- KV epilogue: packed b64 scatter + register ksum ----
        const int hl = wc & 1;                       // head_local (K: wc 0,1; V: wc 2,3)
        short* side = (short*)SMEM + ((wc >= 2) ? 32768 : 0);
        float ks[2][4];
#pragma unroll
        for (int u = 0; u < 2; ++u)
#pragma unroll
            for (int n = 0; n < 4; ++n) ks[u][n] = 0.f;
#pragma unroll
        for (int m = 0; m < 8; ++m) {
            const int ubase = wr * 16384 + (m >> 2) * 8192 + hl * 4096;  // unit*4096
            const int s0 = (m & 3) * 16 + ((l >> 4) << 2);
            const int sc = s0 >> 3, slo = s0 & 7;
#pragma unroll
            for (int n = 0; n < 4; ++n) {
                int d = n * 16 + (l & 15);
                union { short h4[4]; uint2 u2; } pk;
                if (wc < 2) {
                    float e0 = __expf(acc[m][n][0]), e1 = __expf(acc[m][n][1]);
                    float e2 = __expf(acc[m][n][2]), e3 = __expf(acc[m][n][3]);
                    ks[m >> 2][n] += (e0 + e1) + (e2 + e3);
                    pk.h4[0] = f2bf(e0); pk.h4[1] = f2bf(e1);
                    pk.h4[2] = f2bf(e2); pk.h4[3] = f2bf(e3);
                } else {
                    pk.h4[0] = f2bf(acc[m][n][0]); pk.h4[1] = f2bf(acc[m][n][1]);
                    pk.h4[2] = f2bf(acc[m][n][2]); pk.h4[3] = f2bf(acc[m][n][3]);
                }
                *(uint2*)&side[ubase + d * 64 + ((sc ^ swz_f(d)) << 3) + slo] = pk.u2;
            }
        }
        if (wc < 2) {   // finish ksum: lanes l, l^16, l^32 share d
#pragma unroll
            for (int u = 0; u < 2; ++u)
#pragma unroll
                for (int n = 0; n < 4; ++n) {
                    float s = ks[u][n];
                    s += __shfl_xor(s, 16);
                    s += __shfl_xor(s, 32);
                    if ((l >> 4) == 0) {
                        int unit = wr * 4 + u * 2 + hl;
                        int gr0 = brow + (unit >> 1) * 64;
                        size_t bidu = (size_t)(((gr0 >> 12) * 16) + jkv * 2 + (unit & 1)) * 64
                                      + ((gr0 & 4095) >> 6);
                        ksum[bidu * 64 + n * 16 + (l & 15)] = s;
                    }
                }
        }
        __syncthreads();

        // step 2: wave wid owns unit wid; ctx = K^T V (32 MFMA)
        const int gr0 = brow + (wid >> 1) * 64;
        const size_t bid = (size_t)(((gr0 >> 12) * 16) + jkv * 2 + (wid & 1)) * 64
                           + ((gr0 & 4095) >> 6);
        const short* k_u = (const short*)SMEM + wid * 4096;
        const short* v_u = (const short*)SMEM + 32768 + wid * 4096;

        f32x4 a16[4][4];
#pragma unroll
        for (int m = 0; m < 4; ++m)
#pragma unroll
            for (int n = 0; n < 4; ++n) a16[m][n] = (f32x4){0.f, 0.f, 0.f, 0.f};
#pragma unroll
        for (int kk = 0; kk < 2; ++kk) {
            const int cc = kk * 4 + (l >> 4);
            bf16x8s af[4], bf[4];
#pragma unroll
            for (int m = 0; m < 4; ++m) {
                int rA = m * 16 + (l & 15);
                af[m] = *(const bf16x8s*)&k_u[rA * 64 + ((cc ^ swz_f(rA)) << 3)];
                bf[m] = *(const bf16x8s*)&v_u[rA * 64 + ((cc ^ swz_f(rA)) << 3)];
            }
#pragma unroll
            for (int m = 0; m < 4; ++m)
#pragma unroll
                for (int n = 0; n < 4; ++n)
                    a16[m][n] = MFMA16(af[m], bf[n], a16[m][n]);
        }
        bf16* rec = ctxb + bid * 4096;
#pragma unroll
        for (int m = 0; m < 4; ++m) {
            int d0 = m * 16 + ((l >> 4) << 2);
#pragma unroll
            for (int n = 0; n < 4; ++n) {
                int e = n * 16 + (l & 15);
                ushort4 o;
                o.x = (ushort)f2bf(a16[m][n][0]); o.y = (ushort)f2bf(a16[m][n][1]);
                o.z = (ushort)f2bf(a16[m][n][2]); o.w = (ushort)f2bf(a16[m][n][3]);
                *(ushort4*)&rec[e * 64 + d0] = o;
            }
        }
    }
#undef RDA
#undef RDB
#undef GLL
#undef MFMA_BLOCK
#undef BODY
}

// ---------------- exclusive cumsum over buckets ----------------
// grid (5, 64): x<4 -> ctx chains (bf16 in, f32 accum, bf16 out); x==4 -> ksum (f32)
__global__ void cumsum_excl(const bf16* __restrict__ ctxb, const float* __restrict__ ksum,
                            bf16* __restrict__ ctp, float* __restrict__ ksump)
{
    const int bh = blockIdx.y;
    if (blockIdx.x == 4) {
        int d = threadIdx.x;
        if (d >= 64) return;
        float run = 0.f;
        for (int j = 0; j < 64; ++j) {
            size_t idx = (size_t)(bh * 64 + j) * 64 + d;
            float v = ksum[idx];
            ksump[idx] = run;
            run += v;
        }
        return;
    }
    int e0 = (blockIdx.x * 256 + threadIdx.x) * 4;
    float r0 = 0.f, r1 = 0.f, r2 = 0.f, r3 = 0.f;
    for (int j = 0; j < 64; ++j) {
        size_t idx = (size_t)(bh * 64 + j) * 4096 + e0;
        ushort4 v = *(const ushort4*)&ctxb[idx];
        ushort4 o;
        o.x = (ushort)f2bf(r0); o.y = (ushort)f2bf(r1);
        o.z = (ushort)f2bf(r2); o.w = (ushort)f2bf(r3);
        *(ushort4*)&ctp[idx] = o;
        r0 += bf2f((short)v.x); r1 += bf2f((short)v.y);
        r2 += bf2f((short)v.z); r3 += bf2f((short)v.w);
    }
}

// ---------------- den + attn = q @ ctx * Dinv (q pre-softmaxed in GEMM1) ----------------
__global__ __launch_bounds__(256)
void bucket_attn(const bf16* __restrict__ Qb, const bf16* __restrict__ ctp,
                 const float* __restrict__ ksump, bf16* __restrict__ attn)
{
    __shared__ __align__(16) short q_bf[64 * 64];
    __shared__ __align__(16) short ct_bf[64 * 64];
    __shared__ __align__(16) short at_s[64 * 72];
    __shared__ float dinv_s[64];
    __shared__ float ksum_s[64];
    const int bid = blockIdx.x;
    const int bh = bid >> 6, n = bid & 63;
    const int b = bh >> 4, h = bh & 15;
    const size_t rowbase = (size_t)(b * T_SEQ + n * 64) * 1024 + h * 64;
    const int tid = threadIdx.x;
    const int l = tid & 63, w = tid >> 6;

#pragma unroll
    for (int j = 0; j < 2; ++j) {
        int i = tid + 256 * j;
        int e = i >> 3, dc = i & 7;
        bf16x8s cv = *(const bf16x8s*)&ctp[(size_t)bid * 4096 + e * 64 + dc * 8];
        *(bf16x8s*)&ct_bf[e * 64 + ((dc ^ swz_f(e)) << 3)] = cv;
    }
    if (tid < 64) ksum_s[tid] = ksump[(size_t)bid * 64 + tid];
    __syncthreads();

    // den reduce only (softmax already applied in GEMM1)
#pragma unroll
    for (int i = 0; i < 16; ++i) {
        int s = w * 16 + i;
        float qv = bf2f(*(const short*)&Qb[rowbase + (size_t)s * 1024 + l]);
        float dp = qv * ksum_s[l];
#pragma unroll
        for (int off = 32; off; off >>= 1) dp += __shfl_xor(dp, off);
        if (l == 0) dinv_s[s] = 1.f / fmaxf(dp, 1e-6f);
        q_bf[s * 64 + ((((l >> 3)) ^ swz_f(s)) << 3) + (l & 7)] = f2bf(qv);
    }
    __syncthreads();

    f32x4 acc[4];
#pragma unroll
    for (int i = 0; i < 4; ++i) acc[i] = (f32x4){0.f, 0.f, 0.f, 0.f};
    bf16x8s afr[2], bfr[2][4];
#pragma unroll
    for (int kk = 0; kk < 2; ++kk) {
        int cc = kk * 4 + (l >> 4);
        int r = w * 16 + (l & 15);
        afr[kk] = *(const bf16x8s*)&q_bf[r * 64 + ((cc ^ swz_f(r)) << 3)];
#pragma unroll
        for (int n4 = 0; n4 < 4; ++n4) {
            int e = n4 * 16 + (l & 15);
            bfr[kk][n4] = *(const bf16x8s*)&ct_bf[e * 64 + ((cc ^ swz_f(e)) << 3)];
        }
    }
#pragma unroll
    for (int kk = 0; kk < 2; ++kk)
#pragma unroll
        for (int n4 = 0; n4 < 4; ++n4)
            acc[n4] = MFMA16(afr[kk], bfr[kk][n4], acc[n4]);

#pragma unroll
    for (int n4 = 0; n4 < 4; ++n4) {
        int e = n4 * 16 + (l & 15);
#pragma unroll
        for (int r = 0; r < 4; ++r) {
            int s = w * 16 + ((l >> 4) << 2) + r;
            at_s[s * 72 + e] = f2bf(acc[n4][r] * dinv_s[s]);
        }
    }
    __syncthreads();

#pragma unroll
    for (int j = 0; j < 2; ++j) {
        int i = tid + 256 * j;
        int s = i >> 3, c = i & 7;
        bf16x8s v = *(const bf16x8s*)&at_s[s * 72 + c * 8];
        *(bf16x8s*)&attn[rowbase + (size_t)s * 1024 + c * 8] = v;
    }
}

// ---------------- launch ----------------
extern "C" void kernel_launch(void* const* d_in, const int* in_sizes, int n_in,
                              void* d_out, int out_size, void* d_ws, size_t ws_size,
                              hipStream_t stream)
{
    const float* x    = (const float*)d_in[0];
    const float* Wqkv = (const float*)d_in[1];
    const float* Wout = (const float*)d_in[2];

    char* ws = (char*)d_ws;
    size_t off = 0;
    auto alloc = [&](size_t bytes) { void* p = ws + off; off += (bytes + 255) & ~(size_t)255; return p; };
    bf16*  xb    = (bf16*)alloc((size_t)16384 * 1024 * 2);
    bf16*  wqkvb = (bf16*)alloc((size_t)3072 * 1024 * 2);
    bf16*  woutb = (bf16*)alloc((size_t)1024 * 1024 * 2);
    bf16*  Qb    = (bf16*)alloc((size_t)16384 * 1024 * 2);
    bf16*  ctxb  = (bf16*)alloc((size_t)4096 * 4096 * 2);
    float* ksum  = (float*)alloc((size_t)4096 * 64 * 4);
    bf16*  ctp   = (bf16*)alloc((size_t)4096 * 4096 * 2);
    float* ksump = (float*)alloc((size_t)4096 * 64 * 4);
    bf16*  attnb = xb;                       // xb dead after GEMM1 -> reuse
    float* outf  = (float*)d_out;

    cvt_f32_bf16<<<dim3(16384 * 1024 / 8 / 256), 256, 0, stream>>>(x, xb, 16384 * 1024 / 8);
    cvt_f32_bf16<<<dim3(3072 * 1024 / 8 / 256), 256, 0, stream>>>(Wqkv, wqkvb, 3072 * 1024 / 8);
    cvt_f32_bf16<<<dim3(1024 * 1024 / 8 / 256), 256, 0, stream>>>(Wout, woutb, 1024 * 1024 / 8);

    gemm256<0><<<dim3(12, 64), 512, 0, stream>>>(xb, wqkvb, 1024, 3072, Qb, ctxb, ksum, nullptr);
    cumsum_excl<<<dim3(5, 64), 256, 0, stream>>>(ctxb, ksum, ctp, ksump);
    bucket_attn<<<dim3(4096), 256, 0, stream>>>(Qb, ctp, ksump, attnb);
    gemm256<1><<<dim3(4, 64), 512, 0, stream>>>(attnb, woutb, 1024, 1024, nullptr, nullptr, nullptr, outf);
}

// Round 16
// 227.292 us; speedup vs baseline: 1.0796x; 1.0227x over previous
//
#include <hip/hip_runtime.h>
#include <hip/hip_bf16.h>
#include <math.h>

typedef __hip_bfloat16 bf16;
typedef __attribute__((ext_vector_type(4))) float f32x4;
typedef __attribute__((ext_vector_type(8))) short bf16x8s;

#define T_SEQ 4096
#define MFMA16(a, b, c) __builtin_amdgcn_mfma_f32_16x16x32_bf16(a, b, c, 0, 0, 0)
#define AS1 __attribute__((address_space(1)))
#define AS3 __attribute__((address_space(3)))

static __device__ __forceinline__ float bf2f(short u) {
    return __uint_as_float(((unsigned int)(unsigned short)u) << 16);
}
static __device__ __forceinline__ short f2bf(float f) {
    bf16 h = __float2bfloat16(f);
    union { bf16 b; short s; } c; c.b = h; return c.s;
}
static __device__ __forceinline__ int swz_f(int r) { return (r & 7) ^ (r >> 3); }

// ---------------- f32 -> bf16 conversion (vectorized) ----------------
__global__ void cvt_f32_bf16(const float* __restrict__ src, bf16* __restrict__ dst, int n8) {
    int i = blockIdx.x * 256 + threadIdx.x;
    if (i >= n8) return;
    f32x4 a = ((const f32x4*)src)[(size_t)i * 2];
    f32x4 b = ((const f32x4*)src)[(size_t)i * 2 + 1];
    union { bf16 h[8]; uint4 u; } p;
    p.h[0] = __float2bfloat16(a.x); p.h[1] = __float2bfloat16(a.y);
    p.h[2] = __float2bfloat16(a.z); p.h[3] = __float2bfloat16(a.w);
    p.h[4] = __float2bfloat16(b.x); p.h[5] = __float2bfloat16(b.y);
    p.h[6] = __float2bfloat16(b.z); p.h[7] = __float2bfloat16(b.w);
    ((uint4*)dst)[i] = p.u;
}

// ============ 256x256 tile, BK=64, 8-wave pipelined bf16 GEMM ============
// K-halves h=2t+ks ring over 4 LDS slots (slot = h&3, 8KB per matrix side).
// Distance-3 prefetch: while consuming half h, stage half h+3 into slot
// (h+3)&3 = (h-1)&3 (its reads completed >=2 barriers ago -> WAR safe).
// Per half, 2 phases (m0-3 / m4-7, 16 MFMA each, r10 structure):
//   phA: ds_read bfr[4]+afr[0-3] | stage A-part(h+3) | barrier,MFMA,barrier
//   phB: ds_read afr[4-7]        | stage B-part(h+3) | vmcnt(8) | barrier,MFMA,barrier
// Ledger: 4 loads/half; vmcnt(8)@phB(h) leaves halves h+2,h+3 outstanding ->
// half h+1 complete before its phA(h+1) reads (one barrier later, cross-wave ok).
// Prologue: halves 0-2 + vmcnt(8) + barrier. Tail: vmcnt 8 -> 4 -> 0.
// MODE 0 (N-grid 12): bx<4 Q block (f32 softmax epilogue); bx>=4 KV block (fused
// exp(K)/V -> ksum + ctx=K^T V, no K/V to HBM). MODE 1: plain f32 out.
template<int MODE>
__global__ __launch_bounds__(512, 2)
void gemm256(const bf16* __restrict__ A, const bf16* __restrict__ Bm,
             int K, int N,
             bf16* __restrict__ out0, bf16* __restrict__ ctxb, float* __restrict__ ksum,
             float* __restrict__ outf)
{
    __shared__ __align__(16) short SMEM[65536];   // A slots: s*8192 ; B slots: 32768 + s*8192
    const int tid  = threadIdx.x;
    const int l    = tid & 63;
    const int wid  = tid >> 6;
    const int wr   = wid >> 2;           // 0..1
    const int wc   = wid & 3;            // 0..3

    // XCD-chunked bijective swizzle (grid % 8 == 0)
    const int nwg  = gridDim.x * gridDim.y;
    const int flat = blockIdx.y * gridDim.x + blockIdx.x;
    const int swzb = (flat & 7) * (nwg >> 3) + (flat >> 3);
    const int bx   = swzb % gridDim.x;
    const int by   = swzb / gridDim.x;
    const int brow = by * 256;
    const int bcol = bx * 256;
    const int nkt  = K >> 6;             // must be even, >= 4

    const bool isKV = (MODE == 0) && (bx >= 4);
    const int  jkv  = bx - 4;
    const int  b0row = isKV ? (1024 + jkv * 128) : bcol;
    const int  b1row = isKV ? (2048 + jkv * 128) : bcol + 128;

    const int chnk = (l >> 4) ^ (((l & 15) >> 1) & 3);
    const short* baseA = &SMEM[(wr * 128 + (l & 15)) * 32 + chnk * 8];
    const short* baseB = &SMEM[32768 + (wc * 64 + (l & 15)) * 32 + chnk * 8];
#define RDA(SLOT, M_) (*(const bf16x8s*)(baseA + (SLOT) * 8192 + (M_) * 512))
#define RDB(SLOT, N_) (*(const bf16x8s*)(baseB + (SLOT) * 8192 + (N_) * 512))

    const int srow = tid >> 2;
    const int scs  = (tid & 3) ^ ((srow >> 1) & 3);
    const bf16* gA0 = A  + (size_t)(brow + srow) * K + scs * 8;
    const bf16* gA1 = A  + (size_t)(brow + 128 + srow) * K + scs * 8;
    const bf16* gB0 = Bm + (size_t)(b0row + srow) * K + scs * 8;
    const bf16* gB1 = Bm + (size_t)(b1row + srow) * K + scs * 8;
#define GLLH(PTR, SLOT, ISB, EXTRA)                                               \
    __builtin_amdgcn_global_load_lds((const AS1 void*)(PTR),                      \
        (AS3 void*)&SMEM[(ISB) * 32768 + (SLOT) * 8192 + (EXTRA) + tid * 8], 16, 0, 0)

#define VM8 asm volatile("s_waitcnt vmcnt(8)" ::: "memory")
#define VM4 asm volatile("s_waitcnt vmcnt(4)" ::: "memory")
#define VM0 asm volatile("s_waitcnt vmcnt(0)" ::: "memory")
#define VMN ((void)0)

    f32x4 acc[8][4];
#pragma unroll
    for (int m = 0; m < 8; ++m)
#pragma unroll
        for (int n = 0; n < 4; ++n) acc[m][n] = (f32x4){0.f, 0.f, 0.f, 0.f};

    // ---- prologue: stage halves 0,1,2 (issue order = ledger order) ----
#pragma unroll
    for (int h = 0; h < 3; ++h) {
        GLLH(gA0 + h * 32, h, 0, 0);  GLLH(gA1 + h * 32, h, 0, 4096);
        GLLH(gB0 + h * 32, h, 1, 0);  GLLH(gB1 + h * 32, h, 1, 4096);
    }
    VM8;                                  // half 0 complete (h1,h2 in flight)
    __builtin_amdgcn_s_barrier();

    // staging pointers -> half 3
    const bf16 *pA0 = gA0 + 96, *pA1 = gA1 + 96, *pB0 = gB0 + 96, *pB1 = gB1 + 96;

#define MFMA_BLOCK(ACCOFF)                                                        \
    __builtin_amdgcn_s_barrier();                                                 \
    __builtin_amdgcn_s_setprio(1);                                                \
    _Pragma("unroll")                                                             \
    for (int m = 0; m < 4; ++m)                                                   \
        _Pragma("unroll")                                                         \
        for (int n = 0; n < 4; ++n)                                               \
            acc[m + (ACCOFF)][n] = MFMA16(afr[m], bfr[n], acc[m + (ACCOFF)][n]);  \
    __builtin_amdgcn_s_setprio(0);                                                \
    __builtin_amdgcn_s_barrier();

#define HALFSTEP(SLOT, PSLOT, PF, VMW)                                            \
    {                                                                             \
        bf16x8s afr[4], bfr[4];                                                   \
        _Pragma("unroll") for (int n = 0; n < 4; ++n) bfr[n] = RDB(SLOT, n);      \
        _Pragma("unroll") for (int m = 0; m < 4; ++m) afr[m] = RDA(SLOT, m);      \
        if (PF) { GLLH(pA0, PSLOT, 0, 0); GLLH(pA1, PSLOT, 0, 4096); }            \
        MFMA_BLOCK(0)                                                             \
        _Pragma("unroll") for (int m = 0; m < 4; ++m) afr[m] = RDA(SLOT, m + 4);  \
        if (PF) { GLLH(pB0, PSLOT, 1, 0); GLLH(pB1, PSLOT, 1, 4096); }            \
        VMW;                                                                      \
        MFMA_BLOCK(4)                                                             \
        pA0 += 32; pA1 += 32; pB0 += 32; pB1 += 32;                               \
    }

    // main: halves 0 .. 2*nkt-5 (stages 3 .. 2*nkt-2)
    for (int g = 0; g < (nkt >> 1) - 1; ++g) {
        HALFSTEP(0, 3, true, VM8)
        HALFSTEP(1, 0, true, VM8)
        HALFSTEP(2, 1, true, VM8)
        HALFSTEP(3, 2, true, VM8)
    }
    // tail: halves 2nkt-4 .. 2nkt-1 (first stages last half 2nkt-1)
    HALFSTEP(0, 3, true,  VM8)
    HALFSTEP(1, 0, false, VM4)
    HALFSTEP(2, 1, false, VM0)
    HALFSTEP(3, 2, false, VMN)

    if (MODE == 1) {
#pragma unroll
        for (int m = 0; m < 8; ++m) {
            int row = brow + wr * 128 + m * 16 + ((l >> 4) << 2);
#pragma unroll
            for (int n = 0; n < 4; ++n) {
                int col = bcol + wc * 64 + n * 16 + (l & 15);
#pragma unroll
                for (int r = 0; r < 4; ++r)
                    outf[(size_t)(row + r) * N + col] = acc[m][n][r];
            }
        }
    } else if (!isKV) {
        // ---- Q epilogue: f32 row-softmax over the 64-wide head (this wave's wc) ----
#pragma unroll
        for (int m = 0; m < 8; ++m) {
            int row = brow + wr * 128 + m * 16 + ((l >> 4) << 2);
#pragma unroll
            for (int r = 0; r < 4; ++r) {
                float v0 = acc[m][0][r], v1 = acc[m][1][r], v2 = acc[m][2][r], v3 = acc[m][3][r];
                float mx = fmaxf(fmaxf(v0, v1), fmaxf(v2, v3));
#pragma unroll
                for (int off = 8; off; off >>= 1) mx = fmaxf(mx, __shfl_xor(mx, off));
                float e0 = __expf(v0 - mx), e1 = __expf(v1 - mx);
                float e2 = __expf(v2 - mx), e3 = __expf(v3 - mx);
                float sm = e0 + e1 + e2 + e3;
#pragma unroll
                for (int off = 8; off; off >>= 1) sm += __shfl_xor(sm, off);
                float inv = 0.125f / sm;
                size_t rr = (size_t)(row + r);
                int cb = bcol + wc * 64 + (l & 15);
                out0[rr * 1024 + cb]      = __float2bfloat16(e0 * inv);
                out0[rr * 1024 + cb + 16] = __float2bfloat16(e1 * inv);
                out0[rr * 1024 + cb + 32] = __float2bfloat16(e2 * inv);
                out0[rr * 1024 + cb + 48] = __float2bfloat16(e3 * inv);
            }
        }
    } else {
        // ---- KV epilogue: packed b64 scatter + register ksum ----
        const int hl = wc & 1;                       // head_local (K: wc 0,1; V: wc 2,3)
        short* side = (short*)SMEM + ((wc >= 2) ? 32768 : 0);
        float ks[2][4];
#pragma unroll
        for (int u = 0; u < 2; ++u)
#pragma unroll
            for (int n = 0; n < 4; ++n) ks[u][n] = 0.f;
#pragma unroll
        for (int m = 0; m < 8; ++m) {
            const int ubase = wr * 16384 + (m >> 2) * 8192 + hl * 4096;  // unit*4096
            const int s0 = (m & 3) * 16 + ((l >> 4) << 2);
            const int sc = s0 >> 3, slo = s0 & 7;
#pragma unroll
            for (int n = 0; n < 4; ++n) {
                int d = n * 16 + (l & 15);
                union { short h4[4]; uint2 u2; } pk;
                if (wc < 2) {
                    float e0 = __expf(acc[m][n][0]), e1 = __expf(acc[m][n][1]);
                    float e2 = __expf(acc[m][n][2]), e3 = __expf(acc[m][n][3]);
                    ks[m >> 2][n] += (e0 + e1) + (e2 + e3);
                    pk.h4[0] = f2bf(e0); pk.h4[1] = f2bf(e1);
                    pk.h4[2] = f2bf(e2); pk.h4[3] = f2bf(e3);
                } else {
                    pk.h4[0] = f2bf(acc[m][n][0]); pk.h4[1] = f2bf(acc[m][n][1]);
                    pk.h4[2] = f2bf(acc[m][n][2]); pk.h4[3] = f2bf(acc[m][n][3]);
                }
                *(uint2*)&side[ubase + d * 64 + ((sc ^ swz_f(d)) << 3) + slo] = pk.u2;
            }
        }
        if (wc < 2) {   // finish ksum: lanes l, l^16, l^32 share d
#pragma unroll
            for (int u = 0; u < 2; ++u)
#pragma unroll
                for (int n = 0; n < 4; ++n) {
                    float s = ks[u][n];
                    s += __shfl_xor(s, 16);
                    s += __shfl_xor(s, 32);
                    if ((l >> 4) == 0) {
                        int unit = wr * 4 + u * 2 + hl;
                        int gr0 = brow + (unit >> 1) * 64;
                        size_t bidu = (size_t)(((gr0 >> 12) * 16) + jkv * 2 + (unit & 1)) * 64
                                      + ((gr0 & 4095) >> 6);
                        ksum[bidu * 64 + n * 16 + (l & 15)] = s;
                    }
                }
        }
        __syncthreads();

        // step 2: wave wid owns unit wid; ctx = K^T V (32 MFMA)
        const int gr0 = brow + (wid >> 1) * 64;
        const size_t bid = (size_t)(((gr0 >> 12) * 16) + jkv * 2 + (wid & 1)) * 64
                           + ((gr0 & 4095) >> 6);
        const short* k_u = (const short*)SMEM + wid * 4096;
        const short* v_u = (const short*)SMEM + 32768 + wid * 4096;

        f32x4 a16[4][4];
#pragma unroll
        for (int m = 0; m < 4; ++m)
#pragma unroll
            for (int n = 0; n < 4; ++n) a16[m][n] = (f32x4){0.f, 0.f, 0.f, 0.f};
#pragma unroll
        for (int kk = 0; kk < 2; ++kk) {
            const int cc = kk * 4 + (l >> 4);
            bf16x8s af[4], bf[4];
#pragma unroll
            for (int m = 0; m < 4; ++m) {
                int rA = m * 16 + (l & 15);
                af[m] = *(const bf16x8s*)&k_u[rA * 64 + ((cc ^ swz_f(rA)) << 3)];
                bf[m] = *(const bf16x8s*)&v_u[rA * 64 + ((cc ^ swz_f(rA)) << 3)];
            }
#pragma unroll
            for (int m = 0; m < 4; ++m)
#pragma unroll
                for (int n = 0; n < 4; ++n)
                    a16[m][n] = MFMA16(af[m], bf[n], a16[m][n]);
        }
        bf16* rec = ctxb + bid * 4096;
#pragma unroll
        for (int m = 0; m < 4; ++m) {
            int d0 = m * 16 + ((l >> 4) << 2);
#pragma unroll
            for (int n = 0; n < 4; ++n) {
                int e = n * 16 + (l & 15);
                ushort4 o;
                o.x = (ushort)f2bf(a16[m][n][0]); o.y = (ushort)f2bf(a16[m][n][1]);
                o.z = (ushort)f2bf(a16[m][n][2]); o.w = (ushort)f2bf(a16[m][n][3]);
                *(ushort4*)&rec[e * 64 + d0] = o;
            }
        }
    }
#undef RDA
#undef RDB
#undef GLLH
#undef MFMA_BLOCK
#undef HALFSTEP
#undef VM8
#undef VM4
#undef VM0
#undef VMN
}

// ---------------- exclusive cumsum over buckets ----------------
// grid (5, 64): x<4 -> ctx chains (bf16 in, f32 accum, bf16 out); x==4 -> ksum (f32)
__global__ void cumsum_excl(const bf16* __restrict__ ctxb, const float* __restrict__ ksum,
                            bf16* __restrict__ ctp, float* __restrict__ ksump)
{
    const int bh = blockIdx.y;
    if (blockIdx.x == 4) {
        int d = threadIdx.x;
        if (d >= 64) return;
        float run = 0.f;
        for (int j = 0; j < 64; ++j) {
            size_t idx = (size_t)(bh * 64 + j) * 64 + d;
            float v = ksum[idx];
            ksump[idx] = run;
            run += v;
        }
        return;
    }
    int e0 = (blockIdx.x * 256 + threadIdx.x) * 4;
    float r0 = 0.f, r1 = 0.f, r2 = 0.f, r3 = 0.f;
    for (int j = 0; j < 64; ++j) {
        size_t idx = (size_t)(bh * 64 + j) * 4096 + e0;
        ushort4 v = *(const ushort4*)&ctxb[idx];
        ushort4 o;
        o.x = (ushort)f2bf(r0); o.y = (ushort)f2bf(r1);
        o.z = (ushort)f2bf(r2); o.w = (ushort)f2bf(r3);
        *(ushort4*)&ctp[idx] = o;
        r0 += bf2f((short)v.x); r1 += bf2f((short)v.y);
        r2 += bf2f((short)v.z); r3 += bf2f((short)v.w);
    }
}

// ---------------- den + attn = q @ ctx * Dinv (q pre-softmaxed in GEMM1) ----------------
__global__ __launch_bounds__(256)
void bucket_attn(const bf16* __restrict__ Qb, const bf16* __restrict__ ctp,
                 const float* __restrict__ ksump, bf16* __restrict__ attn)
{
    __shared__ __align__(16) short q_bf[64 * 64];
    __shared__ __align__(16) short ct_bf[64 * 64];
    __shared__ __align__(16) short at_s[64 * 72];
    __shared__ float dinv_s[64];
    __shared__ float ksum_s[64];
    const int bid = blockIdx.x;
    const int bh = bid >> 6, n = bid & 63;
    const int b = bh >> 4, h = bh & 15;
    const size_t rowbase = (size_t)(b * T_SEQ + n * 64) * 1024 + h * 64;
    const int tid = threadIdx.x;
    const int l = tid & 63, w = tid >> 6;

#pragma unroll
    for (int j = 0; j < 2; ++j) {
        int i = tid + 256 * j;
        int e = i >> 3, dc = i & 7;
        bf16x8s cv = *(const bf16x8s*)&ctp[(size_t)bid * 4096 + e * 64 + dc * 8];
        *(bf16x8s*)&ct_bf[e * 64 + ((dc ^ swz_f(e)) << 3)] = cv;
    }
    if (tid < 64) ksum_s[tid] = ksump[(size_t)bid * 64 + tid];
    __syncthreads();

    // den reduce only (softmax already applied in GEMM1)
#pragma unroll
    for (int i = 0; i < 16; ++i) {
        int s = w * 16 + i;
        float qv = bf2f(*(const short*)&Qb[rowbase + (size_t)s * 1024 + l]);
        float dp = qv * ksum_s[l];
#pragma unroll
        for (int off = 32; off; off >>= 1) dp += __shfl_xor(dp, off);
        if (l == 0) dinv_s[s] = 1.f / fmaxf(dp, 1e-6f);
        q_bf[s * 64 + ((((l >> 3)) ^ swz_f(s)) << 3) + (l & 7)] = f2bf(qv);
    }
    __syncthreads();

    f32x4 acc[4];
#pragma unroll
    for (int i = 0; i < 4; ++i) acc[i] = (f32x4){0.f, 0.f, 0.f, 0.f};
    bf16x8s afr[2], bfr[2][4];
#pragma unroll
    for (int kk = 0; kk < 2; ++kk) {
        int cc = kk * 4 + (l >> 4);
        int r = w * 16 + (l & 15);
        afr[kk] = *(const bf16x8s*)&q_bf[r * 64 + ((cc ^ swz_f(r)) << 3)];
#pragma unroll
        for (int n4 = 0; n4 < 4; ++n4) {
            int e = n4 * 16 + (l & 15);
            bfr[kk][n4] = *(const bf16x8s*)&ct_bf[e * 64 + ((cc ^ swz_f(e)) << 3)];
        }
    }
#pragma unroll
    for (int kk = 0; kk < 2; ++kk)
#pragma unroll
        for (int n4 = 0; n4 < 4; ++n4)
            acc[n4] = MFMA16(afr[kk], bfr[kk][n4], acc[n4]);

#pragma unroll
    for (int n4 = 0; n4 < 4; ++n4) {
        int e = n4 * 16 + (l & 15);
#pragma unroll
        for (int r = 0; r < 4; ++r) {
            int s = w * 16 + ((l >> 4) << 2) + r;
            at_s[s * 72 + e] = f2bf(acc[n4][r] * dinv_s[s]);
        }
    }
    __syncthreads();

#pragma unroll
    for (int j = 0; j < 2; ++j) {
        int i = tid + 256 * j;
        int s = i >> 3, c = i & 7;
        bf16x8s v = *(const bf16x8s*)&at_s[s * 72 + c * 8];
        *(bf16x8s*)&attn[rowbase + (size_t)s * 1024 + c * 8] = v;
    }
}

// ---------------- launch ----------------
extern "C" void kernel_launch(void* const* d_in, const int* in_sizes, int n_in,
                              void* d_out, int out_size, void* d_ws, size_t ws_size,
                              hipStream_t stream)
{
    const float* x    = (const float*)d_in[0];
    const float* Wqkv = (const float*)d_in[1];
    const float* Wout = (const float*)d_in[2];

    char* ws = (char*)d_ws;
    size_t off = 0;
    auto alloc = [&](size_t bytes) { void* p = ws + off; off += (bytes + 255) & ~(size_t)255; return p; };
    bf16*  xb    = (bf16*)alloc((size_t)16384 * 1024 * 2);
    bf16*  wqkvb = (bf16*)alloc((size_t)3072 * 1024 * 2);
    bf16*  woutb = (bf16*)alloc((size_t)1024 * 1024 * 2);
    bf16*  Qb    = (bf16*)alloc((size_t)16384 * 1024 * 2);
    bf16*  ctxb  = (bf16*)alloc((size_t)4096 * 4096 * 2);
    float* ksum  = (float*)alloc((size_t)4096 * 64 * 4);
    bf16*  ctp   = (bf16*)alloc((size_t)4096 * 4096 * 2);
    float* ksump = (float*)alloc((size_t)4096 * 64 * 4);
    bf16*  attnb = xb;                       // xb dead after GEMM1 -> reuse
    float* outf  = (float*)d_out;

    cvt_f32_bf16<<<dim3(16384 * 1024 / 8 / 256), 256, 0, stream>>>(x, xb, 16384 * 1024 / 8);
    cvt_f32_bf16<<<dim3(3072 * 1024 / 8 / 256), 256, 0, stream>>>(Wqkv, wqkvb, 3072 * 1024 / 8);
    cvt_f32_bf16<<<dim3(1024 * 1024 / 8 / 256), 256, 0, stream>>>(Wout, woutb, 1024 * 1024 / 8);

    gemm256<0><<<dim3(12, 64), 512, 0, stream>>>(xb, wqkvb, 1024, 3072, Qb, ctxb, ksum, nullptr);
    cumsum_excl<<<dim3(5, 64), 256, 0, stream>>>(ctxb, ksum, ctp, ksump);
    bucket_attn<<<dim3(4096), 256, 0, stream>>>(Qb, ctp, ksump, attnb);
    gemm256<1><<<dim3(4, 64), 512, 0, stream>>>(attnb, woutb, 1024, 1024, nullptr, nullptr, nullptr, outf);
}